// Round 1
// baseline (4428.857 us; speedup 1.0000x reference)
//
#include <hip/hip_runtime.h>
#include <stdint.h>

// ---------------------------------------------------------------------------
// LSTMSingle: emb gather + x@W_ih^T precompute (K1, f16 MFMA) ->
// grouped persistent LSTM recurrence (K2: 8 groups x 16 wgs, W_hh register-
// resident fragments, f16 MFMA, ping-pong h buffers + per-group atomic
// barrier) -> final FC (K3, f16 MFMA, HBM-bound on W_fc).
// All matmuls f16 inputs / fp32 accumulate; cell state c kept fp32 in LDS.
// ---------------------------------------------------------------------------

#define NB   128
#define LMAX 512
#define HD   512
#define G4   2048
#define NV   50000

// workspace layout (bytes)
#define H0_OFF   0          // f16 [128][512] h ping
#define H1_OFF   131072     // f16 [128][512] h pong
#define C_OFF    262144     // f32 [128][512] cell state
#define CNT_OFF  524288     // 8 group counters, padded 64B apart
#define XP_OFF   525312     // f16 [128][TC][2048] x_proj chunk
#define INIT_W4  32832      // 525312/16 : zeroed every call by k0

typedef _Float16 f16;
typedef _Float16 half8  __attribute__((ext_vector_type(8)));
typedef float    float4v __attribute__((ext_vector_type(4)));
typedef uint32_t u32x4  __attribute__((ext_vector_type(4)));

__device__ __forceinline__ half8 cvt8(const float* p) {
  float4v a = *(const float4v*)p;
  float4v b = *(const float4v*)(p + 4);
  half8 r;
  r[0] = (f16)a[0]; r[1] = (f16)a[1]; r[2] = (f16)a[2]; r[3] = (f16)a[3];
  r[4] = (f16)b[0]; r[5] = (f16)b[1]; r[6] = (f16)b[2]; r[7] = (f16)b[3];
  return r;
}

__device__ __forceinline__ float sigmoidf_(float x) {
  return 1.0f / (1.0f + __expf(-x));
}
__device__ __forceinline__ float tanhf_(float x) {
  return 1.0f - 2.0f / (1.0f + __expf(2.0f * x));   // exact limits at +-inf
}

// ---------------------------------------------------------------- K0: init
extern "C" __global__ void k0_init(u32x4* ws4) {
  int idx = blockIdx.x * 256 + threadIdx.x;
  u32x4 z = {0u, 0u, 0u, 0u};
  if (idx < INIT_W4) ws4[idx] = z;
}

// -------------------------------------------------------------- K1: x_proj
// grid (b, m-tile-of-64-t, n-tile-of-128-g); wg = 256 thr (4 waves).
// A = emb rows (gathered, f16-cvt, 64KB LDS, XOR-swizzled granules),
// B = W_ih rows loaded as fragments from global with inline cvt.
extern "C" __global__ void __launch_bounds__(256)
k1_xproj(const int* __restrict__ tokens, const int* __restrict__ lengths,
         const float* __restrict__ emb, const float* __restrict__ Wih,
         const float* __restrict__ bih, const float* __restrict__ bhh,
         f16* __restrict__ xp, int t0c, int TC) {
  int b  = blockIdx.x;
  int mt = blockIdx.y;
  int nt = blockIdx.z;
  int len = lengths[b];
  int t0 = t0c + mt * 64;
  if (t0 >= len) return;                      // whole tile past this seq

  __shared__ f16 As[64 * 512];                // 64 KB, swizzled
  int tid = threadIdx.x;

  #pragma unroll
  for (int it = 0; it < 16; ++it) {
    int gl = tid + 256 * it;                  // granule id: 64 rows x 64
    int row = gl >> 6, gi = gl & 63;
    int tok = tokens[b * LMAX + t0 + row];    // rows past len: harmless load
    half8 v = cvt8(emb + (size_t)tok * HD + gi * 8);
    *(half8*)&As[row * 512 + ((gi ^ (row & 7)) * 8)] = v;
  }
  __syncthreads();

  int wave = tid >> 6, lane = tid & 63;
  int quad = lane >> 4, l15 = lane & 15;
  int col0 = nt * 128 + wave * 32;

  float4v acc[4][2] = {};
  for (int c = 0; c < 16; ++c) {
    half8 b0 = cvt8(Wih + (size_t)(col0 + l15) * HD + c * 32 + quad * 8);
    half8 b1 = cvt8(Wih + (size_t)(col0 + 16 + l15) * HD + c * 32 + quad * 8);
    #pragma unroll
    for (int mm = 0; mm < 4; ++mm) {
      int row = mm * 16 + l15;
      half8 a = *(const half8*)&As[row * 512 + (((c * 4 + quad) ^ (row & 7)) * 8)];
      acc[mm][0] = __builtin_amdgcn_mfma_f32_16x16x32_f16(a, b0, acc[mm][0], 0, 0, 0);
      acc[mm][1] = __builtin_amdgcn_mfma_f32_16x16x32_f16(a, b1, acc[mm][1], 0, 0, 0);
    }
  }

  // epilogue: + (b_ih + b_hh), cvt f16, store ragged-masked
  #pragma unroll
  for (int q = 0; q < 2; ++q) {
    int gcol = col0 + q * 16 + l15;
    float bias = bih[gcol] + bhh[gcol];
    #pragma unroll
    for (int mm = 0; mm < 4; ++mm) {
      #pragma unroll
      for (int j = 0; j < 4; ++j) {
        int t = t0 + mm * 16 + quad * 4 + j;
        if (t < len)
          xp[((size_t)b * TC + (t - t0c)) * G4 + gcol] = (f16)(acc[mm][q][j] + bias);
      }
    }
  }
}

// ---------------------------------------------------------- K2: recurrence
// 128 wgs: group g = wg&7 handles seqs [16g,16g+16); member m = wg>>3 owns
// h-columns [32m,32m+32) i.e. gate rows {blk*512+32m..+32} for blk=i,f,g,o.
// W_hh fragments live in VGPRs for the whole launch (128 VGPRs/lane).
// h exchanged via ping-pong global f16 buffers + per-group counter barrier.
extern "C" __global__ void __launch_bounds__(256)
k2_lstm(const int* __restrict__ lengths, const float* __restrict__ Whh,
        const f16* __restrict__ xp, f16* __restrict__ h0buf,
        f16* __restrict__ h1buf, float* __restrict__ cbuf,
        unsigned int* __restrict__ cnt, int t0c, int TC) {
  int wg = blockIdx.x;
  int grp = wg & 7, memb = wg >> 3;
  int s0 = grp * 16;
  int tid = threadIdx.x;

  int gm = 0;
  for (int i = 0; i < 16; ++i) { int l = lengths[s0 + i]; gm = l > gm ? l : gm; }
  int tend = (t0c + TC < gm) ? (t0c + TC) : gm;
  if (t0c >= tend) return;                    // whole group done; uniform

  __shared__ f16   Hs[16 * 512];              // group h, swizzled granules
  __shared__ float gates[16][132];            // +4 pad: 2-way banks only
  __shared__ float cst[16][33];               // fp32 cell state slice

  int wave = tid >> 6, lane = tid & 63;
  int quad = lane >> 4, l15 = lane & 15;

  // register-resident W_hh fragments: wave w <-> gate block w
  half8 wf0[16], wf1[16];
  {
    const float* r0 = Whh + (size_t)(wave * 512 + memb * 32 + l15) * HD;
    const float* r1 = Whh + (size_t)(wave * 512 + memb * 32 + 16 + l15) * HD;
    #pragma unroll
    for (int c = 0; c < 16; ++c) {
      wf0[c] = cvt8(r0 + c * 32 + quad * 8);
      wf1[c] = cvt8(r1 + c * 32 + quad * 8);
    }
  }

  // elementwise coords: this thread owns (sA,kk) and (sB,kk)
  int sA = tid >> 5, sB = sA + 8, kk = tid & 31;
  int lenA = lengths[s0 + sA], lenB = lengths[s0 + sB];
  cst[sA][kk] = cbuf[(size_t)(s0 + sA) * HD + memb * 32 + kk];
  cst[sB][kk] = cbuf[(size_t)(s0 + sB) * HD + memb * 32 + kk];

  unsigned int* flag = cnt + grp * 16;        // 64B-padded counter

  for (int t = t0c; t < tend; ++t) {
    const f16* hin  = (t & 1) ? h1buf : h0buf;
    f16*       hout = (t & 1) ? h0buf : h1buf;

    // stage group's h into LDS (swizzled)
    #pragma unroll
    for (int r = 0; r < 4; ++r) {
      int gl = tid + 256 * r;                 // 16 seqs x 64 granules
      int s = gl >> 6, gi = gl & 63;
      half8 v = *(const half8*)&hin[(size_t)(s0 + s) * HD + gi * 8];
      *(half8*)&Hs[s * 512 + ((gi ^ (s & 7)) * 8)] = v;
    }

    // prefetch x_proj gate contributions (independent of h -> hides latency)
    float xiA = 0, xfA = 0, xgA = 0, xoA = 0;
    float xiB = 0, xfB = 0, xgB = 0, xoB = 0;
    bool validA = t < lenA, validB = t < lenB;
    if (validA) {
      const f16* p = xp + ((size_t)(s0 + sA) * TC + (t - t0c)) * G4 + memb * 32 + kk;
      xiA = (float)p[0]; xfA = (float)p[512]; xgA = (float)p[1024]; xoA = (float)p[1536];
    }
    if (validB) {
      const f16* p = xp + ((size_t)(s0 + sB) * TC + (t - t0c)) * G4 + memb * 32 + kk;
      xiB = (float)p[0]; xfB = (float)p[512]; xgB = (float)p[1024]; xoB = (float)p[1536];
    }
    __syncthreads();

    // gates = h @ W_hh^T : two 16x16 tiles per wave, 2 acc chains each
    float4v a0e = {}, a0o = {}, a1e = {}, a1o = {};
    #pragma unroll
    for (int c = 0; c < 16; ++c) {
      half8 a = *(const half8*)&Hs[l15 * 512 + (((c * 4 + quad) ^ (l15 & 7)) * 8)];
      if (c & 1) {
        a0o = __builtin_amdgcn_mfma_f32_16x16x32_f16(a, wf0[c], a0o, 0, 0, 0);
        a1o = __builtin_amdgcn_mfma_f32_16x16x32_f16(a, wf1[c], a1o, 0, 0, 0);
      } else {
        a0e = __builtin_amdgcn_mfma_f32_16x16x32_f16(a, wf0[c], a0e, 0, 0, 0);
        a1e = __builtin_amdgcn_mfma_f32_16x16x32_f16(a, wf1[c], a1e, 0, 0, 0);
      }
    }
    float4v g0 = a0e + a0o, g1 = a1e + a1o;
    #pragma unroll
    for (int j = 0; j < 4; ++j) {             // D: row=quad*4+j (seq), col=l15
      gates[quad * 4 + j][wave * 32 + l15]      = g0[j];
      gates[quad * 4 + j][wave * 32 + 16 + l15] = g1[j];
    }
    __syncthreads();

    // LSTM cell update for the wg's 32 h-columns (i,f,g,o = col blocks)
    {
      size_t oA = (size_t)(s0 + sA) * HD + memb * 32 + kk;
      if (validA) {
        float ii = sigmoidf_(gates[sA][kk]      + xiA);
        float ff = sigmoidf_(gates[sA][32 + kk] + xfA);
        float gg = tanhf_   (gates[sA][64 + kk] + xgA);
        float oo = sigmoidf_(gates[sA][96 + kk] + xoA);
        float cn = ff * cst[sA][kk] + ii * gg;
        cst[sA][kk] = cn;
        hout[oA] = (f16)(oo * tanhf_(cn));
      } else {                                // frozen: carry state forward
        hout[oA] = Hs[sA * 512 + (((memb * 4 + (kk >> 3)) ^ (sA & 7)) * 8) + (kk & 7)];
      }
      size_t oB = (size_t)(s0 + sB) * HD + memb * 32 + kk;
      if (validB) {
        float ii = sigmoidf_(gates[sB][kk]      + xiB);
        float ff = sigmoidf_(gates[sB][32 + kk] + xfB);
        float gg = tanhf_   (gates[sB][64 + kk] + xgB);
        float oo = sigmoidf_(gates[sB][96 + kk] + xoB);
        float cn = ff * cst[sB][kk] + ii * gg;
        cst[sB][kk] = cn;
        hout[oB] = (f16)(oo * tanhf_(cn));
      } else {
        hout[oB] = Hs[sB * 512 + (((memb * 4 + (kk >> 3)) ^ (sB & 7)) * 8) + (kk & 7)];
      }
    }

    // group barrier: release own h writes, wait for all 16 members
    __syncthreads();
    if (tid == 0) {
      __threadfence();
      __hip_atomic_fetch_add(flag, 1u, __ATOMIC_RELEASE, __HIP_MEMORY_SCOPE_AGENT);
      unsigned int target = 16u * (unsigned int)(t + 1);
      while (__hip_atomic_load(flag, __ATOMIC_RELAXED, __HIP_MEMORY_SCOPE_AGENT) < target)
        __builtin_amdgcn_s_sleep(1);
      __threadfence();
    }
    __syncthreads();
  }

  // persist cell state for next chunk launch
  cbuf[(size_t)(s0 + sA) * HD + memb * 32 + kk] = cst[sA][kk];
  cbuf[(size_t)(s0 + sB) * HD + memb * 32 + kk] = cst[sB][kk];

  // normalize: ensure final h lives in h0buf for K3
  if (tend == gm && (gm & 1)) {
    size_t oA = (size_t)(s0 + sA) * HD + memb * 32 + kk;
    size_t oB = (size_t)(s0 + sB) * HD + memb * 32 + kk;
    h0buf[oA] = h1buf[oA];
    h0buf[oB] = h1buf[oB];
  }
}

// ----------------------------------------------------------------- K3: FC
// out[128,50000] = hT @ W_fc^T + b_fc. HBM-bound on W_fc (102 MB).
extern "C" __global__ void __launch_bounds__(256)
k3_fc(const f16* __restrict__ hT, const float* __restrict__ Wfc,
      const float* __restrict__ bfc, float* __restrict__ out) {
  int tid = threadIdx.x;
  int wave = tid >> 6, lane = tid & 63, quad = lane >> 4, l15 = lane & 15;
  int v = blockIdx.x * 64 + wave * 16 + l15;
  int vc = v < NV ? v : NV - 1;               // clamp loads, guard stores
  float4v acc[8] = {};
  for (int c = 0; c < 16; ++c) {
    half8 bfr = cvt8(Wfc + (size_t)vc * HD + c * 32 + quad * 8);
    #pragma unroll
    for (int mt = 0; mt < 8; ++mt) {
      half8 afr = *(const half8*)&hT[(size_t)(mt * 16 + l15) * HD + c * 32 + quad * 8];
      acc[mt] = __builtin_amdgcn_mfma_f32_16x16x32_f16(afr, bfr, acc[mt], 0, 0, 0);
    }
  }
  if (v < NV) {
    float bias = bfc[v];
    #pragma unroll
    for (int mt = 0; mt < 8; ++mt)
      #pragma unroll
      for (int j = 0; j < 4; ++j)
        out[(size_t)(mt * 16 + quad * 4 + j) * NV + v] = acc[mt][j] + bias;
  }
}

// ---------------------------------------------------------------- launcher
extern "C" void kernel_launch(void* const* d_in, const int* in_sizes, int n_in,
                              void* d_out, int out_size, void* d_ws, size_t ws_size,
                              hipStream_t stream) {
  (void)in_sizes; (void)n_in; (void)out_size;
  const int*   tokens  = (const int*)d_in[0];
  const int*   lengths = (const int*)d_in[1];
  const float* emb     = (const float*)d_in[2];
  const float* Wih     = (const float*)d_in[3];
  const float* Whh     = (const float*)d_in[4];
  const float* bih     = (const float*)d_in[5];
  const float* bhh     = (const float*)d_in[6];
  const float* Wfc     = (const float*)d_in[7];
  const float* bfc     = (const float*)d_in[8];
  float* out = (float*)d_out;
  char* ws = (char*)d_ws;

  f16* h0 = (f16*)(ws + H0_OFF);
  f16* h1 = (f16*)(ws + H1_OFF);
  float* cbuf = (float*)(ws + C_OFF);
  unsigned int* cnt = (unsigned int*)(ws + CNT_OFF);
  f16* xp = (f16*)(ws + XP_OFF);

  // pick largest time-chunk whose x_proj staging fits the workspace
  int TC = 512;
  while (TC > 64 && (size_t)XP_OFF + (size_t)NB * TC * G4 * 2 > ws_size) TC >>= 1;

  hipLaunchKernelGGL(k0_init, dim3(129), dim3(256), 0, stream, (u32x4*)ws);
  for (int t0 = 0; t0 < LMAX; t0 += TC) {
    hipLaunchKernelGGL(k1_xproj, dim3(NB, TC / 64, 16), dim3(256), 0, stream,
                       tokens, lengths, emb, Wih, bih, bhh, xp, t0, TC);
    hipLaunchKernelGGL(k2_lstm, dim3(128), dim3(256), 0, stream,
                       lengths, Whh, xp, h0, h1, cbuf, cnt, t0, TC);
  }
  hipLaunchKernelGGL(k3_fc, dim3((NV + 63) / 64), dim3(256), 0, stream,
                     h0, Wfc, bfc, out);
}

// Round 2
// 3003.220 us; speedup vs baseline: 1.4747x; 1.4747x over previous
//
#include <hip/hip_runtime.h>
#include <stdint.h>

// ---------------------------------------------------------------------------
// LSTMSingle v2:
//  K0  zero h/c/counters; Kcvt preconvert emb + W_ih to f16 in ws.
//  K1  x_proj GEMM (f16 MFMA, f16 operands, no cvt in inner loop).
//  K2  recurrence: 64 wgs = 4 pairs x 16 membs; each wg serves TWO groups of
//      16 seqs (A/B interleaved) with register-resident W_hh fragments.
//      h exchanged via AGENT-scope relaxed atomics (sc1 -> Infinity Cache,
//      bypasses stale per-XCD L2) -> NO threadfence / buffer_wbl2 / buffer_inv.
//      Barrier = relaxed counter add after syncthreads (vmcnt drain) + poll.
//  K3  final FC, HBM-bound on W_fc.
// ---------------------------------------------------------------------------

#define NB   128
#define LMAX 512
#define HD   512
#define G4   2048
#define NV   50000

// workspace layout (bytes)
#define H0_OFF      0
#define H1_OFF      131072
#define C_OFF       262144
#define CNT_OFF     524288
#define EMB16_OFF   525312
#define EMB16_BYTES (NV * HD * 2)                    // 51,200,000
#define WIH16_OFF   (EMB16_OFF + EMB16_BYTES)
#define WIH16_BYTES (G4 * HD * 2)                    // 2,097,152
#define XP_OFF      (WIH16_OFF + WIH16_BYTES)
#define INIT_W4     32832                            // 525312/16

typedef _Float16 f16;
typedef _Float16 half8  __attribute__((ext_vector_type(8)));
typedef float    float4v __attribute__((ext_vector_type(4)));
typedef uint32_t u32;
typedef unsigned long long u64;
typedef uint32_t u32x4 __attribute__((ext_vector_type(4)));

__device__ __forceinline__ half8 cvt8(const float* p) {
  float4v a = *(const float4v*)p;
  float4v b = *(const float4v*)(p + 4);
  half8 r;
  r[0] = (f16)a[0]; r[1] = (f16)a[1]; r[2] = (f16)a[2]; r[3] = (f16)a[3];
  r[4] = (f16)b[0]; r[5] = (f16)b[1]; r[6] = (f16)b[2]; r[7] = (f16)b[3];
  return r;
}
__device__ __forceinline__ float sigmoidf_(float x) { return 1.0f / (1.0f + __expf(-x)); }
__device__ __forceinline__ float tanhf_(float x)    { return 1.0f - 2.0f / (1.0f + __expf(2.0f * x)); }

// ---------------------------------------------------------------- K0: init
extern "C" __global__ void k0_init(u32x4* ws4) {
  int idx = blockIdx.x * 256 + threadIdx.x;
  u32x4 z = {0u, 0u, 0u, 0u};
  if (idx < INIT_W4) ws4[idx] = z;
}

// ------------------------------------------------------------- Kcvt: f32->f16
extern "C" __global__ void __launch_bounds__(256)
k_cvt(const float* __restrict__ src, f16* __restrict__ dst, int n8) {
  int i = blockIdx.x * 256 + threadIdx.x;
  if (i >= n8) return;
  ((half8*)dst)[i] = cvt8(src + (size_t)i * 8);
}

// -------------------------------------------------------------- K1: x_proj
extern "C" __global__ void __launch_bounds__(256)
k1_xproj(const int* __restrict__ tokens, const int* __restrict__ lengths,
         const f16* __restrict__ emb16, const f16* __restrict__ wih16,
         const float* __restrict__ bih, const float* __restrict__ bhh,
         f16* __restrict__ xp, int t0c, int TC) {
  int b  = blockIdx.x;
  int mt = blockIdx.y;
  int nt = blockIdx.z;
  int len = lengths[b];
  int t0 = t0c + mt * 64;
  if (t0 >= len) return;

  __shared__ f16 As[64 * 512];                // 64 KB, XOR-swizzled granules
  int tid = threadIdx.x;

  #pragma unroll
  for (int it = 0; it < 16; ++it) {
    int gl = tid + 256 * it;
    int row = gl >> 6, gi = gl & 63;
    int tok = tokens[b * LMAX + t0 + row];
    half8 v = *(const half8*)(emb16 + (size_t)tok * HD + gi * 8);
    *(half8*)&As[row * 512 + ((gi ^ (row & 7)) * 8)] = v;
  }
  __syncthreads();

  int wave = tid >> 6, lane = tid & 63;
  int quad = lane >> 4, l15 = lane & 15;
  int col0 = nt * 128 + wave * 32;

  float4v acc[4][2] = {};
  for (int c = 0; c < 16; ++c) {
    half8 b0 = *(const half8*)(wih16 + (size_t)(col0 + l15) * HD + c * 32 + quad * 8);
    half8 b1 = *(const half8*)(wih16 + (size_t)(col0 + 16 + l15) * HD + c * 32 + quad * 8);
    #pragma unroll
    for (int mm = 0; mm < 4; ++mm) {
      int row = mm * 16 + l15;
      half8 a = *(const half8*)&As[row * 512 + (((c * 4 + quad) ^ (row & 7)) * 8)];
      acc[mm][0] = __builtin_amdgcn_mfma_f32_16x16x32_f16(a, b0, acc[mm][0], 0, 0, 0);
      acc[mm][1] = __builtin_amdgcn_mfma_f32_16x16x32_f16(a, b1, acc[mm][1], 0, 0, 0);
    }
  }

  #pragma unroll
  for (int q = 0; q < 2; ++q) {
    int gcol = col0 + q * 16 + l15;
    float bias = bih[gcol] + bhh[gcol];
    #pragma unroll
    for (int mm = 0; mm < 4; ++mm) {
      #pragma unroll
      for (int j = 0; j < 4; ++j) {
        int t = t0 + mm * 16 + quad * 4 + j;
        if (t < len)
          xp[((size_t)b * TC + (t - t0c)) * G4 + gcol] = (f16)(acc[mm][q][j] + bias);
      }
    }
  }
}

// ---------------------------------------------------------- K2: recurrence
// 64 wgs: pair p = wg&3 serves groups {2p, 2p+1}; memb m = wg>>2 owns
// h-columns [32m,32m+32). W_hh fragments register-resident (shared by both
// groups). All h traffic = agent-scope relaxed atomics (Infinity Cache).
extern "C" __global__ void __launch_bounds__(256, 1)
k2_lstm(const int* __restrict__ lengths, const float* __restrict__ Whh,
        const f16* __restrict__ xp, f16* __restrict__ h0buf,
        f16* __restrict__ h1buf, float* __restrict__ cbuf,
        u32* __restrict__ cnt, int t0c, int TC) {
  int wg = blockIdx.x;
  int pair = wg & 3, memb = wg >> 2;
  int grpA = pair * 2, grpB = grpA + 1;
  int s0A = grpA * 16, s0B = grpB * 16;
  int tid = threadIdx.x;

  int gmA = 0, gmB = 0;
  for (int i = 0; i < 16; ++i) { int l = lengths[s0A + i]; gmA = l > gmA ? l : gmA; }
  for (int i = 0; i < 16; ++i) { int l = lengths[s0B + i]; gmB = l > gmB ? l : gmB; }
  int tendA = (t0c + TC < gmA) ? (t0c + TC) : gmA;
  int tendB = (t0c + TC < gmB) ? (t0c + TC) : gmB;
  int tmax = tendA > tendB ? tendA : tendB;
  if (t0c >= tmax) return;

  __shared__ f16 HsA[16 * 512], HsB[16 * 512];     // 32 KB
  __shared__ float gA[16][133], gB[16][133];       // padded: odd stride

  int wave = tid >> 6, lane = tid & 63;
  int quad = lane >> 4, l15 = lane & 15;

  // register-resident W_hh fragments: wave w <-> gate block w
  half8 wf0[16], wf1[16];
  {
    const float* r0 = Whh + (size_t)(wave * 512 + memb * 32 + l15) * HD;
    const float* r1 = r0 + (size_t)16 * HD;
    #pragma unroll
    for (int c = 0; c < 16; ++c) {
      wf0[c] = cvt8(r0 + c * 32 + quad * 8);
      wf1[c] = cvt8(r1 + c * 32 + quad * 8);
    }
  }

  // elementwise: thread owns (seq sE, 2 cols kk0..kk0+1) in each group
  int sE = tid >> 4, kE = tid & 15, kk0 = kE * 2;
  int lenA = lengths[s0A + sE], lenB = lengths[s0B + sE];
  float cA0 = cbuf[(size_t)(s0A + sE) * HD + memb * 32 + kk0];
  float cA1 = cbuf[(size_t)(s0A + sE) * HD + memb * 32 + kk0 + 1];
  float cB0 = cbuf[(size_t)(s0B + sE) * HD + memb * 32 + kk0];
  float cB1 = cbuf[(size_t)(s0B + sE) * HD + memb * 32 + kk0 + 1];

  const f16* hin0 = (t0c & 1) ? h1buf : h0buf;
  u32 hpA = __hip_atomic_load((const u32*)hin0 + (size_t)(s0A + sE) * 256 + memb * 16 + kE,
                              __ATOMIC_RELAXED, __HIP_MEMORY_SCOPE_AGENT);
  u32 hpB = __hip_atomic_load((const u32*)hin0 + (size_t)(s0B + sE) * 256 + memb * 16 + kE,
                              __ATOMIC_RELAXED, __HIP_MEMORY_SCOPE_AGENT);

  u32* flagA = cnt + grpA * 16;
  u32* flagB = cnt + grpB * 16;

  for (int t = t0c; t < tmax; ++t) {
    bool actA = t < tendA, actB = t < tendB;
    const f16* hin  = (t & 1) ? h1buf : h0buf;
    f16*       hout = (t & 1) ? h0buf : h1buf;

    u64 avA[8], avB[8];
    // --- wait barrier + issue h staging loads (A first, B overlaps A latency)
    if (actA) {
      if (tid == 0) {
        u32 tg = 16u * (u32)t;
        while (__hip_atomic_load(flagA, __ATOMIC_RELAXED, __HIP_MEMORY_SCOPE_AGENT) < tg)
          __builtin_amdgcn_s_sleep(2);
      }
      __syncthreads();
      #pragma unroll
      for (int r = 0; r < 4; ++r) {
        int gl = tid + 256 * r, s = gl >> 6, gi = gl & 63;
        const u64* p = (const u64*)(hin + (size_t)(s0A + s) * HD + gi * 8);
        avA[2 * r]     = __hip_atomic_load(p,     __ATOMIC_RELAXED, __HIP_MEMORY_SCOPE_AGENT);
        avA[2 * r + 1] = __hip_atomic_load(p + 1, __ATOMIC_RELAXED, __HIP_MEMORY_SCOPE_AGENT);
      }
    }
    if (actB) {
      if (tid == 0) {
        u32 tg = 16u * (u32)t;
        while (__hip_atomic_load(flagB, __ATOMIC_RELAXED, __HIP_MEMORY_SCOPE_AGENT) < tg)
          __builtin_amdgcn_s_sleep(2);
      }
      __syncthreads();
      #pragma unroll
      for (int r = 0; r < 4; ++r) {
        int gl = tid + 256 * r, s = gl >> 6, gi = gl & 63;
        const u64* p = (const u64*)(hin + (size_t)(s0B + s) * HD + gi * 8);
        avB[2 * r]     = __hip_atomic_load(p,     __ATOMIC_RELAXED, __HIP_MEMORY_SCOPE_AGENT);
        avB[2 * r + 1] = __hip_atomic_load(p + 1, __ATOMIC_RELAXED, __HIP_MEMORY_SCOPE_AGENT);
      }
    }

    // --- xp prefetch (plain cached loads; written by K1 in a prior kernel)
    u32 xA[4], xB[4];
    bool vA = actA && (t < lenA), vB = actB && (t < lenB);
    if (vA) {
      const f16* p = xp + ((size_t)(s0A + sE) * TC + (t - t0c)) * G4 + memb * 32 + kk0;
      xA[0] = *(const u32*)p;          xA[1] = *(const u32*)(p + 512);
      xA[2] = *(const u32*)(p + 1024); xA[3] = *(const u32*)(p + 1536);
    }
    if (vB) {
      const f16* p = xp + ((size_t)(s0B + sE) * TC + (t - t0c)) * G4 + memb * 32 + kk0;
      xB[0] = *(const u32*)p;          xB[1] = *(const u32*)(p + 512);
      xB[2] = *(const u32*)(p + 1024); xB[3] = *(const u32*)(p + 1536);
    }

    // =================== phase A compute ===================
    if (actA) {
      #pragma unroll
      for (int r = 0; r < 4; ++r) {
        int gl = tid + 256 * r, s = gl >> 6, gi = gl & 63;
        union { u64 u[2]; half8 h; } w;
        w.u[0] = avA[2 * r]; w.u[1] = avA[2 * r + 1];
        *(half8*)&HsA[s * 512 + ((gi ^ (s & 7)) * 8)] = w.h;
      }
      __syncthreads();
      float4v a0e = {}, a0o = {}, a1e = {}, a1o = {};
      #pragma unroll
      for (int c = 0; c < 16; ++c) {
        half8 a = *(const half8*)&HsA[l15 * 512 + (((c * 4 + quad) ^ (l15 & 7)) * 8)];
        if (c & 1) {
          a0o = __builtin_amdgcn_mfma_f32_16x16x32_f16(a, wf0[c], a0o, 0, 0, 0);
          a1o = __builtin_amdgcn_mfma_f32_16x16x32_f16(a, wf1[c], a1o, 0, 0, 0);
        } else {
          a0e = __builtin_amdgcn_mfma_f32_16x16x32_f16(a, wf0[c], a0e, 0, 0, 0);
          a1e = __builtin_amdgcn_mfma_f32_16x16x32_f16(a, wf1[c], a1e, 0, 0, 0);
        }
      }
      float4v g0 = a0e + a0o, g1 = a1e + a1o;
      #pragma unroll
      for (int j = 0; j < 4; ++j) {
        gA[quad * 4 + j][wave * 32 + l15]      = g0[j];
        gA[quad * 4 + j][wave * 32 + 16 + l15] = g1[j];
      }
      __syncthreads();
      if (vA) {
        union { u32 u; f16 h[2]; } xi, xf, xg, xo, hp;
        xi.u = xA[0]; xf.u = xA[1]; xg.u = xA[2]; xo.u = xA[3];
        float i0 = sigmoidf_(gA[sE][kk0]          + (float)xi.h[0]);
        float i1 = sigmoidf_(gA[sE][kk0 + 1]      + (float)xi.h[1]);
        float f0 = sigmoidf_(gA[sE][32 + kk0]     + (float)xf.h[0]);
        float f1 = sigmoidf_(gA[sE][32 + kk0 + 1] + (float)xf.h[1]);
        float q0 = tanhf_  (gA[sE][64 + kk0]      + (float)xg.h[0]);
        float q1 = tanhf_  (gA[sE][64 + kk0 + 1]  + (float)xg.h[1]);
        float o0 = sigmoidf_(gA[sE][96 + kk0]     + (float)xo.h[0]);
        float o1 = sigmoidf_(gA[sE][96 + kk0 + 1] + (float)xo.h[1]);
        cA0 = f0 * cA0 + i0 * q0;
        cA1 = f1 * cA1 + i1 * q1;
        hp.h[0] = (f16)(o0 * tanhf_(cA0));
        hp.h[1] = (f16)(o1 * tanhf_(cA1));
        hpA = hp.u;
      }
      __hip_atomic_store((u32*)hout + (size_t)(s0A + sE) * 256 + memb * 16 + kE, hpA,
                         __ATOMIC_RELAXED, __HIP_MEMORY_SCOPE_AGENT);
      __builtin_amdgcn_s_waitcnt(0x0f70);          // vmcnt(0): stores acked
      __syncthreads();
      if (tid == 0)
        __hip_atomic_fetch_add(flagA, 1u, __ATOMIC_RELAXED, __HIP_MEMORY_SCOPE_AGENT);
    }

    // =================== phase B compute ===================
    if (actB) {
      #pragma unroll
      for (int r = 0; r < 4; ++r) {
        int gl = tid + 256 * r, s = gl >> 6, gi = gl & 63;
        union { u64 u[2]; half8 h; } w;
        w.u[0] = avB[2 * r]; w.u[1] = avB[2 * r + 1];
        *(half8*)&HsB[s * 512 + ((gi ^ (s & 7)) * 8)] = w.h;
      }
      __syncthreads();
      float4v a0e = {}, a0o = {}, a1e = {}, a1o = {};
      #pragma unroll
      for (int c = 0; c < 16; ++c) {
        half8 a = *(const half8*)&HsB[l15 * 512 + (((c * 4 + quad) ^ (l15 & 7)) * 8)];
        if (c & 1) {
          a0o = __builtin_amdgcn_mfma_f32_16x16x32_f16(a, wf0[c], a0o, 0, 0, 0);
          a1o = __builtin_amdgcn_mfma_f32_16x16x32_f16(a, wf1[c], a1o, 0, 0, 0);
        } else {
          a0e = __builtin_amdgcn_mfma_f32_16x16x32_f16(a, wf0[c], a0e, 0, 0, 0);
          a1e = __builtin_amdgcn_mfma_f32_16x16x32_f16(a, wf1[c], a1e, 0, 0, 0);
        }
      }
      float4v g0 = a0e + a0o, g1 = a1e + a1o;
      #pragma unroll
      for (int j = 0; j < 4; ++j) {
        gB[quad * 4 + j][wave * 32 + l15]      = g0[j];
        gB[quad * 4 + j][wave * 32 + 16 + l15] = g1[j];
      }
      __syncthreads();
      if (vB) {
        union { u32 u; f16 h[2]; } xi, xf, xg, xo, hp;
        xi.u = xB[0]; xf.u = xB[1]; xg.u = xB[2]; xo.u = xB[3];
        float i0 = sigmoidf_(gB[sE][kk0]          + (float)xi.h[0]);
        float i1 = sigmoidf_(gB[sE][kk0 + 1]      + (float)xi.h[1]);
        float f0 = sigmoidf_(gB[sE][32 + kk0]     + (float)xf.h[0]);
        float f1 = sigmoidf_(gB[sE][32 + kk0 + 1] + (float)xf.h[1]);
        float q0 = tanhf_  (gB[sE][64 + kk0]      + (float)xg.h[0]);
        float q1 = tanhf_  (gB[sE][64 + kk0 + 1]  + (float)xg.h[1]);
        float o0 = sigmoidf_(gB[sE][96 + kk0]     + (float)xo.h[0]);
        float o1 = sigmoidf_(gB[sE][96 + kk0 + 1] + (float)xo.h[1]);
        cB0 = f0 * cB0 + i0 * q0;
        cB1 = f1 * cB1 + i1 * q1;
        hp.h[0] = (f16)(o0 * tanhf_(cB0));
        hp.h[1] = (f16)(o1 * tanhf_(cB1));
        hpB = hp.u;
      }
      __hip_atomic_store((u32*)hout + (size_t)(s0B + sE) * 256 + memb * 16 + kE, hpB,
                         __ATOMIC_RELAXED, __HIP_MEMORY_SCOPE_AGENT);
      __builtin_amdgcn_s_waitcnt(0x0f70);
      __syncthreads();
      if (tid == 0)
        __hip_atomic_fetch_add(flagB, 1u, __ATOMIC_RELAXED, __HIP_MEMORY_SCOPE_AGENT);
    }
  }

  // persist cell state
  cbuf[(size_t)(s0A + sE) * HD + memb * 32 + kk0]     = cA0;
  cbuf[(size_t)(s0A + sE) * HD + memb * 32 + kk0 + 1] = cA1;
  cbuf[(size_t)(s0B + sE) * HD + memb * 32 + kk0]     = cB0;
  cbuf[(size_t)(s0B + sE) * HD + memb * 32 + kk0 + 1] = cB1;

  // normalize: final h -> h0buf (only when the group finished in THIS chunk)
  if (gmA > t0c && tendA == gmA && (gmA & 1))
    __hip_atomic_store((u32*)h0buf + (size_t)(s0A + sE) * 256 + memb * 16 + kE, hpA,
                       __ATOMIC_RELAXED, __HIP_MEMORY_SCOPE_AGENT);
  if (gmB > t0c && tendB == gmB && (gmB & 1))
    __hip_atomic_store((u32*)h0buf + (size_t)(s0B + sE) * 256 + memb * 16 + kE, hpB,
                       __ATOMIC_RELAXED, __HIP_MEMORY_SCOPE_AGENT);
}

// ----------------------------------------------------------------- K3: FC
extern "C" __global__ void __launch_bounds__(256)
k3_fc(const f16* __restrict__ hT, const float* __restrict__ Wfc,
      const float* __restrict__ bfc, float* __restrict__ out) {
  int tid = threadIdx.x;
  int wave = tid >> 6, lane = tid & 63, quad = lane >> 4, l15 = lane & 15;
  int v = blockIdx.x * 64 + wave * 16 + l15;
  int vc = v < NV ? v : NV - 1;
  float4v acc[8] = {};
  for (int c = 0; c < 16; ++c) {
    half8 bfr = cvt8(Wfc + (size_t)vc * HD + c * 32 + quad * 8);
    #pragma unroll
    for (int mt = 0; mt < 8; ++mt) {
      half8 afr = *(const half8*)&hT[(size_t)(mt * 16 + l15) * HD + c * 32 + quad * 8];
      acc[mt] = __builtin_amdgcn_mfma_f32_16x16x32_f16(afr, bfr, acc[mt], 0, 0, 0);
    }
  }
  if (v < NV) {
    float bias = bfc[v];
    #pragma unroll
    for (int mt = 0; mt < 8; ++mt)
      #pragma unroll
      for (int j = 0; j < 4; ++j)
        out[(size_t)(mt * 16 + quad * 4 + j) * NV + v] = acc[mt][j] + bias;
  }
}

// ---------------------------------------------------------------- launcher
extern "C" void kernel_launch(void* const* d_in, const int* in_sizes, int n_in,
                              void* d_out, int out_size, void* d_ws, size_t ws_size,
                              hipStream_t stream) {
  (void)in_sizes; (void)n_in; (void)out_size;
  const int*   tokens  = (const int*)d_in[0];
  const int*   lengths = (const int*)d_in[1];
  const float* emb     = (const float*)d_in[2];
  const float* Wih     = (const float*)d_in[3];
  const float* Whh     = (const float*)d_in[4];
  const float* bih     = (const float*)d_in[5];
  const float* bhh     = (const float*)d_in[6];
  const float* Wfc     = (const float*)d_in[7];
  const float* bfc     = (const float*)d_in[8];
  float* out = (float*)d_out;
  char* ws = (char*)d_ws;

  f16* h0 = (f16*)(ws + H0_OFF);
  f16* h1 = (f16*)(ws + H1_OFF);
  float* cbuf = (float*)(ws + C_OFF);
  u32* cnt = (u32*)(ws + CNT_OFF);
  f16* emb16 = (f16*)(ws + EMB16_OFF);
  f16* wih16 = (f16*)(ws + WIH16_OFF);
  f16* xp = (f16*)(ws + XP_OFF);

  int TC = 512;
  while (TC > 64 && (size_t)XP_OFF + (size_t)NB * TC * G4 * 2 > ws_size) TC >>= 1;

  hipLaunchKernelGGL(k0_init, dim3(129), dim3(256), 0, stream, (u32x4*)ws);
  hipLaunchKernelGGL(k_cvt, dim3((NV * HD / 8 + 255) / 256), dim3(256), 0, stream,
                     emb, emb16, NV * HD / 8);
  hipLaunchKernelGGL(k_cvt, dim3((G4 * HD / 8 + 255) / 256), dim3(256), 0, stream,
                     Wih, wih16, G4 * HD / 8);
  for (int t0 = 0; t0 < LMAX; t0 += TC) {
    hipLaunchKernelGGL(k1_xproj, dim3(NB, TC / 64, 16), dim3(256), 0, stream,
                       tokens, lengths, emb16, wih16, bih, bhh, xp, t0, TC);
    hipLaunchKernelGGL(k2_lstm, dim3(64), dim3(256), 0, stream,
                       lengths, Whh, xp, h0, h1, cbuf, cnt, t0, TC);
  }
  hipLaunchKernelGGL(k3_fc, dim3((NV + 63) / 64), dim3(256), 0, stream,
                     h0, Wfc, bfc, out);
}